// Round 9
// baseline (449.864 us; speedup 1.0000x reference)
//
#include <hip/hip_runtime.h>
#include <hip/hip_bf16.h>
#include <math.h>
#include <stdint.h>

typedef __hip_bfloat16 bf16;
typedef __attribute__((ext_vector_type(8))) short short8;   // 8 x bf16 (4 VGPRs)
typedef __attribute__((ext_vector_type(4))) float f32x4;
typedef __attribute__((ext_vector_type(2))) unsigned int u32x2;

#define NB 16384
#define HID 768
#define EPS_LN 1e-5f
#define LAM_INIT 0.2f       // 0.8 - 0.6*exp(-0.3*0)

__device__ __forceinline__ float bf2f(bf16 x){ return __bfloat162float(x); }
__device__ __forceinline__ bf16  f2bf(float x){ return __float2bfloat16(x); }
__device__ __forceinline__ float bfbits(uint32_t lo16){ return __uint_as_float(lo16 << 16); }
__device__ __forceinline__ uint32_t f2bfbits(float x){
  union { float f; uint32_t u; } v; v.f = x;
  uint32_t u = v.u;
  uint32_t r = (u + 0x7fff + ((u >> 16) & 1)) >> 16;   // RNE
  return r;
}

template<typename T> __device__ __forceinline__ float ldv(const void* p, int i);
template<> __device__ __forceinline__ float ldv<float>(const void* p, int i){ return ((const float*)p)[i]; }
template<> __device__ __forceinline__ float ldv<bf16 >(const void* p, int i){ return bf2f(((const bf16*)p)[i]); }

template<typename T> __device__ __forceinline__ void stv(T* p, float v);
template<> __device__ __forceinline__ void stv<float>(float* p, float v){ *p = v; }
template<> __device__ __forceinline__ void stv<bf16 >(bf16*  p, float v){ *p = f2bf(v); }

__device__ __forceinline__ void async_copy16(void* lds, const void* g){
  __builtin_amdgcn_global_load_lds(
      (const __attribute__((address_space(1))) unsigned int*)g,
      (__attribute__((address_space(3))) unsigned int*)lds, 16, 0, 0);
}

__device__ __forceinline__ float wred64(float v){
  #pragma unroll
  for (int m = 1; m <= 32; m <<= 1) v += __shfl_xor(v, m, 64);
  return v;
}

// dtype detect: bf16 inputs have etab row 8 (zeros) at byte offset 512..575.
__device__ __forceinline__ int detect_bf(const void* etab){
  const uint32_t* p = (const uint32_t*)((const char*)etab + 512);
  uint32_t v = 0;
  #pragma unroll
  for (int i = 0; i < 16; ++i) v |= p[i];
  return v == 0u ? 1 : 0;
}

// prep float layout:
//   [0]=flag(int), [1]=lam
//   [16+s*32+p]=cos, [128+s*32+p]=sin            (legacy layout, p<24)
//   [256 + (s*24+p)*2 .. +1] = packed {cos,sin}  (p<24)
//   [512+id]=mean(E1[id]), [528+id]=E[E1[id]^2], [544+id]=E[E1[id]*b1]
//   [560]=mean(b1), [561]=E[b1^2]
//   [1024 .. 1024+9*768) = E1 = etab @ W1  (9 x 768, f32)

// ---- setup part 1: lambda + RoPE tables (one block, wave 0) -----------------
__device__ __forceinline__ void misc_body(int isbf, const void* lq1, const void* lk1,
                                          const void* lq2, const void* lk2, float* prep){
  const int lane = threadIdx.x;
  if (lane >= 64) return;
  if (lane == 0) ((int*)prep)[0] = isbf;

  float p1 = 0.f, p2 = 0.f;
  if (lane < 48){
    if (isbf){ p1 = ldv<bf16>(lq1,lane)*ldv<bf16>(lk1,lane); p2 = ldv<bf16>(lq2,lane)*ldv<bf16>(lk2,lane); }
    else     { p1 = ldv<float>(lq1,lane)*ldv<float>(lk1,lane); p2 = ldv<float>(lq2,lane)*ldv<float>(lk2,lane); }
  }
  p1 = wred64(p1); p2 = wred64(p2);
  if (lane == 0) prep[1] = expf(p1) - expf(p2) + LAM_INIT;

  if (lane < 24){
    float invf = powf(10000.f, -(float)(2*lane)/48.f);
    #pragma unroll
    for (int s=0;s<3;++s){
      float ang = (float)s*invf;
      float c = cosf(ang), sv = sinf(ang);
      prep[16  + s*32 + lane] = c;
      prep[128 + s*32 + lane] = sv;
      prep[256 + (s*24 + lane)*2    ] = c;
      prep[256 + (s*24 + lane)*2 + 1] = sv;
    }
  }
}

// ---- setup part 2: E1 = etab @ W1 (one block per id) + closed-form LN stats -
template<typename T>
__device__ __forceinline__ void prep_e1_body(int id, const void* etab, const void* W1,
                                             const void* b1, float* prep,
                                             float (*red)[4]){
  const int tid = threadIdx.x;
  const int wave = tid >> 6, lane = tid & 63;

  float et[32];
  #pragma unroll
  for (int e=0;e<32;++e) et[e] = ldv<T>(etab, id*32+e);

  float su=0.f, suu=0.f, sub=0.f;
  #pragma unroll
  for (int q=0;q<3;++q){
    const int cc = tid + q*256;
    float s = 0.f;
    #pragma unroll
    for (int e=0;e<32;++e) s += et[e]*ldv<T>(W1, e*HID+cc);
    prep[1024 + id*HID + cc] = s;
    float bv = ldv<T>(b1, cc);
    su += s; suu += s*s; sub += s*bv;
  }
  su = wred64(su); suu = wred64(suu); sub = wred64(sub);
  if (lane==0){ red[0][wave]=su; red[1][wave]=suu; red[2][wave]=sub; }
  __syncthreads();
  if (tid==0){
    float a=0.f,b=0.f,c=0.f;
    #pragma unroll
    for (int w=0;w<4;++w){ a+=red[0][w]; b+=red[1][w]; c+=red[2][w]; }
    prep[512+id]=a*(1.f/768.f); prep[528+id]=b*(1.f/768.f); prep[544+id]=c*(1.f/768.f);
  }
  if (id==0){
    float sb=0.f, sbb=0.f;
    #pragma unroll
    for (int q=0;q<3;++q){ float bv=ldv<T>(b1, tid+q*256); sb+=bv; sbb+=bv*bv; }
    sb=wred64(sb); sbb=wred64(sbb);
    __syncthreads();                       // red[] free again
    if (lane==0){ red[0][wave]=sb; red[1][wave]=sbb; }
    __syncthreads();
    if (tid==0){
      float a=0.f,b=0.f;
      #pragma unroll
      for (int w=0;w<4;++w){ a+=red[0][w]; b+=red[1][w]; }
      prep[560]=a*(1.f/768.f); prep[561]=b*(1.f/768.f);
    }
  }
}

// ---- setup part 3: weight transpose (K,N) -> bf16 (N,K) ---------------------
template<typename T>
__device__ __forceinline__ void transpose_body(bf16 (*tile)[33], const void* src,
                                               bf16* dst, int n0, int k0){
  const int tid = threadIdx.x;
  const int tx = tid & 31, ty = tid >> 5;
  #pragma unroll
  for (int r=0;r<4;++r)
    tile[ty + 8*r][tx] = f2bf(ldv<T>(src, (k0 + ty + 8*r)*HID + n0 + tx));
  __syncthreads();
  #pragma unroll
  for (int r=0;r<4;++r)
    dst[(size_t)(n0 + ty + 8*r)*HID + k0 + tx] = tile[tx][ty + 8*r];
}

// ---- one setup launch: blocks [0,2304) transpose, 2304 misc, [2305,2314) E1 -
__global__ __launch_bounds__(256) void setup_kernel(
    const void* etab, const void* W1, const void* b1,
    const void* lq1, const void* lk1, const void* lq2, const void* lk2,
    const void* Wq, const void* Wk, const void* Wv, const void* Wo,
    bf16* __restrict__ WqkvT, bf16* __restrict__ WoT, float* prep)
{
  __shared__ bf16 tile[32][33];
  __shared__ float red[3][4];
  const int bid = blockIdx.x;
  const int isbf = detect_bf(etab);
  if (bid < 2304){
    const int z = bid / 576, rem = bid % 576;
    const int bx = rem % 24, by = rem / 24;
    const void* src = (z==0)? Wq : (z==1)? Wk : (z==2)? Wv : Wo;
    bf16* dst = (z<3)? (WqkvT + (size_t)z*HID*HID) : WoT;
    if (isbf) transpose_body<bf16 >(tile, src, dst, bx*32, by*32);
    else      transpose_body<float>(tile, src, dst, bx*32, by*32);
  } else if (bid == 2304){
    misc_body(isbf, lq1, lk1, lq2, lk2, prep);
  } else {
    if (isbf) prep_e1_body<bf16 >(bid-2305, etab, W1, b1, prep, red);
    else      prep_e1_body<float>(bid-2305, etab, W1, b1, prep, red);
  }
}

// -------- embed via E1 table: h = gelu(LN(conf*E1[id] + b1)) -----------------
// 512-thread variant: 8 waves x 4 tokens = 32 tokens/block.
template<typename T>
__device__ __forceinline__ void embed_body(
    int ebid, const int* eidx, const void* conf, const void* b1, const void* lng,
    const void* lnb, const float* prep, bf16* hout, int tok0)
{
  const int wave = threadIdx.x >> 6, lane = threadIdx.x & 63;
  const int t0 = ebid*32 + wave*4;
  const int c  = lane*12;
  float bb[12], gg[12], be[12];
  #pragma unroll
  for (int d=0;d<12;++d){ bb[d]=ldv<T>(b1,c+d); gg[d]=ldv<T>(lng,c+d); be[d]=ldv<T>(lnb,c+d); }
  const float m_b = prep[560], s_bb = prep[561];
  const float* E1 = prep + 1024;

  #pragma unroll
  for (int tt = 0; tt < 4; ++tt){
    const int tl = t0 + tt, tg = tok0 + tl;
    int id = eidx[tg]; if (id < 0) id = 8;
    const float cf = ldv<T>(conf, tg);
    const float4* ep = (const float4*)(E1 + id*HID + c);
    float4 u0 = ep[0], u1 = ep[1], u2 = ep[2];
    float u[12] = {u0.x,u0.y,u0.z,u0.w, u1.x,u1.y,u1.z,u1.w, u2.x,u2.y,u2.z,u2.w};
    const float mu  = cf*prep[512+id] + m_b;
    const float ex2 = cf*cf*prep[528+id] + 2.f*cf*prep[544+id] + s_bb;
    const float var = ex2 - mu*mu;
    const float rs  = rsqrtf(fmaxf(var, 0.f) + EPS_LN);
    uint32_t w[6];
    #pragma unroll
    for (int d=0;d<6;++d){
      float x0 = cf*u[2*d]   + bb[2*d];
      float x1 = cf*u[2*d+1] + bb[2*d+1];
      float y0 = (x0-mu)*rs*gg[2*d]   + be[2*d];
      float y1 = (x1-mu)*rs*gg[2*d+1] + be[2*d+1];
      float g0 = 0.5f*y0*(1.f + erff(y0*0.70710678118f));
      float g1 = 0.5f*y1*(1.f + erff(y1*0.70710678118f));
      w[d] = f2bfbits(g0) | (f2bfbits(g1) << 16);
    }
    char* op = (char*)hout + (size_t)(tl*HID + c)*2;
    ((u32x2*)op)[0] = (u32x2){w[0],w[1]};
    ((u32x2*)op)[1] = (u32x2){w[2],w[3]};
    ((u32x2*)op)[2] = (u32x2){w[4],w[5]};
  }
}

// ---------------- attention: one wave per batch row (all 8 heads) ------------
// 512-thread variant: 8 rows/block.
template<typename T>
__device__ __forceinline__ void attn_body(
    int abid, const bf16* __restrict__ qkv, const int* __restrict__ eidx,
    const void* subw, bf16* __restrict__ obar, int b0, const float* prep)
{
  const int bl = abid*8 + (threadIdx.x>>6);         // chunk-local batch row
  const int bg = b0 + bl;                           // global batch row
  const int lane = threadIdx.x & 63;
  const int h  = lane >> 3;
  const int u  = lane & 7;
  const int g  = u >> 2;
  const int qd = u & 3;

  float npad[3];
  #pragma unroll
  for (int s=0;s<3;++s){ int id = eidx[bg*3+s]; npad[s] = (id < 0 || id == 8) ? 0.f : 1.f; }
  float denom = npad[0]+npad[1]+npad[2]; if (denom < 1.f) denom = 1.f;
  const float lam = prep[1];
  const float2* pk = (const float2*)(prep + 256);

  const char* base = (const char*)(qkv + (size_t)bl*3*2304);
  const int qoff = (2*h+g)*48 + qd*12;              // element offset in token row

  u32x2 qw[3][3], kw[3][3];
  #pragma unroll
  for (int s=0;s<3;++s){
    const char* qp = base + (size_t)(s*2304 + qoff)*2;
    const char* kp = qp + 768*2;
    #pragma unroll
    for (int t=0;t<3;++t){
      qw[s][t] = *(const u32x2*)(qp + t*8);
      kw[s][t] = *(const u32x2*)(kp + t*8);
    }
  }

  float sc[3][3];
  #pragma unroll
  for (int a=0;a<3;++a){ sc[a][0]=0.f; sc[a][1]=0.f; sc[a][2]=0.f; }
  #pragma unroll
  for (int j=0;j<6;++j){
    float qr1[3], qr2[3], kr1[3], kr2[3];
    #pragma unroll
    for (int s=0;s<3;++s){
      float2 cs = pk[s*24 + qd*6 + j];
      uint32_t qu = qw[s][j>>1][j&1], ku = kw[s][j>>1][j&1];
      float q1 = bfbits(qu & 0xffffu), q2 = bfbits(qu >> 16);
      float k1 = bfbits(ku & 0xffffu), k2 = bfbits(ku >> 16);
      qr1[s] = q1*cs.x - q2*cs.y;  qr2[s] = q1*cs.y + q2*cs.x;
      kr1[s] = k1*cs.x - k2*cs.y;  kr2[s] = k1*cs.y + k2*cs.x;
    }
    #pragma unroll
    for (int a=0;a<3;++a)
      #pragma unroll
      for (int b=0;b<3;++b) sc[a][b] += qr1[a]*kr1[b] + qr2[a]*kr2[b];
  }
  #pragma unroll
  for (int a=0;a<3;++a)
    #pragma unroll
    for (int b=0;b<3;++b){
      float v = sc[a][b];
      v += __shfl_xor(v, 1, 64);
      v += __shfl_xor(v, 2, 64);
      sc[a][b] = v;
    }

  const float scale = 0.14433756729740643f;  // 48^-0.5
  float att[3][3];
  #pragma unroll
  for (int a=0;a<3;++a){
    float s0 = sc[a][0]*scale + (npad[0] > 0.f ? 0.f : -1e30f);
    float s1 = sc[a][1]*scale + (npad[1] > 0.f ? 0.f : -1e30f);
    float s2 = sc[a][2]*scale + (npad[2] > 0.f ? 0.f : -1e30f);
    float mx = fmaxf(s0, fmaxf(s1, s2));
    float e0 = expf(s0-mx), e1 = expf(s1-mx), e2 = expf(s2-mx);
    float inv = 1.f/(e0+e1+e2);
    att[a][0]=e0*inv; att[a][1]=e1*inv; att[a][2]=e2*inv;
  }
  float diff[3][3];
  #pragma unroll
  for (int a=0;a<3;++a)
    #pragma unroll
    for (int b=0;b<3;++b){
      float other = __shfl_xor(att[a][b], 4, 64);
      diff[a][b] = (g==0) ? (att[a][b] - lam*other) : (other - lam*att[a][b]);
    }

  const int vd = u*12;
  float vv[3][12];
  #pragma unroll
  for (int s=0;s<3;++s){
    const char* vp = base + (size_t)(s*2304 + 1536 + h*96 + vd)*2;
    #pragma unroll
    for (int t=0;t<3;++t){
      u32x2 w = *(const u32x2*)(vp + t*8);
      vv[s][t*4+0] = bfbits(w[0] & 0xffffu);
      vv[s][t*4+1] = bfbits(w[0] >> 16);
      vv[s][t*4+2] = bfbits(w[1] & 0xffffu);
      vv[s][t*4+3] = bfbits(w[1] >> 16);
    }
  }
  float sw[12];
  #pragma unroll
  for (int d=0;d<12;++d) sw[d] = ldv<T>(subw, vd + d);

  float acc[12];
  #pragma unroll
  for (int d=0;d<12;++d) acc[d] = 0.f;
  #pragma unroll
  for (int a=0;a<3;++a){
    float o[12]; float ss = 0.f;
    #pragma unroll
    for (int d=0;d<12;++d){
      o[d] = diff[a][0]*vv[0][d] + diff[a][1]*vv[1][d] + diff[a][2]*vv[2][d];
      ss += o[d]*o[d];
    }
    ss += __shfl_xor(ss, 1, 64);
    ss += __shfl_xor(ss, 2, 64);
    ss += __shfl_xor(ss, 4, 64);                  // sum over 96 dims of head h
    float rms = sqrtf(ss*(1.f/96.f) + 1e-5f);
    float kk  = npad[a]*0.8f/rms;                 // includes *(1-LAMBDA_INIT)
    #pragma unroll
    for (int d=0;d<12;++d) acc[d] += o[d]*kk*sw[d];
  }
  const float idn = 1.f/denom;
  char* op = (char*)obar + (size_t)(bg*HID + h*96 + vd)*2;
  #pragma unroll
  for (int t=0;t<3;++t){
    u32x2 w;
    w[0] = f2bfbits(acc[t*4+0]*idn) | (f2bfbits(acc[t*4+1]*idn) << 16);
    w[1] = f2bfbits(acc[t*4+2]*idn) | (f2bfbits(acc[t*4+3]*idn) << 16);
    *(u32x2*)(op + t*8) = w;
  }
}

// ------- 128x128 MFMA GEMM, 8 waves: dbuf + XCD swizzle + LDS XOR swizzle ----
// (round-8 proven: 512thr, wave grid 4Mx2N, 64KB LDS, 52 VGPR, 0 conflicts,
// ~111us at 24576x2304x768.)
template<typename OutT>
__device__ __forceinline__ void gemm_body(int bid,
    bf16* sA, bf16* sB,     // each 2*128*64 elements (two buffers)
    const bf16* __restrict__ A, const bf16* __restrict__ Bt, OutT* __restrict__ C,
    int K, int lda, int ldb, int ldc, int MT, int NT)
{
  int mt, nt;
  if ((MT & 7) == 0) {
    int x = bid & 7, j = bid >> 3;
    nt = j % NT;
    mt = x * (MT >> 3) + j / NT;
  } else { nt = bid % NT; mt = bid / NT; }

  const int tid = threadIdx.x;
  const int wave = tid >> 6, lane = tid & 63;       // wave 0..7
  const int m0 = mt * 128, n0 = nt * 128;
  const int wm = wave >> 1, wn = wave & 1;          // 4M x 2N wave grid

  f32x4 acc[2][4];
  #pragma unroll
  for (int i=0;i<2;++i)
    #pragma unroll
    for (int j=0;j<4;++j) acc[i][j] = (f32x4){0.f,0.f,0.f,0.f};

  const char* Ag = (const char*)(A  + (size_t)m0 * lda);
  const char* Bg = (const char*)(Bt + (size_t)n0 * ldb);
  const int r8  = lane >> 3;                       // row within 8-row group (0..7)
  const int cBx = ((lane & 7) ^ r8) * 16;          // XOR-permuted k-group source

  #define STAGE(buf, kt) do {                                                   \
    _Pragma("unroll")                                                           \
    for (int ii = 0; ii < 2; ++ii) {                                            \
      const int i_ = wave*2 + ii;                                               \
      const int row_ = i_*8 + r8;                                               \
      async_copy16((char*)sA + (buf)*16384 + i_*1024 + lane*16,                 \
                   Ag + ((size_t)row_*lda + (kt))*2 + cBx);                     \
      async_copy16((char*)sB + (buf)*16384 + i_*1024 + lane*16,                 \
                   Bg + ((size_t)row_*ldb + (kt))*2 + cBx);                     \
    }                                                                           \
  } while(0)

  STAGE(0, 0);
  int cur = 0;
  const int rxor = (lane & 7) << 3;                // reader phys-k XOR (row&7)*8
  for (int kt = 0; kt < K; kt += 64) {
    __syncthreads();
    if (kt + 64 < K) STAGE(cur^1, kt + 64);   // prefetch overlaps compute below
    const bf16* pA = sA + cur*8192;
    const bf16* pB = sB + cur*8192;
    #pragma unroll
    for (int ks = 0; ks < 64; ks += 32) {
      const int kq = (ks + (lane >> 4)*8) ^ rxor;
      short8 af[2], bfv[4];
      #pragma unroll
      for (int i=0;i<2;++i)
        af[i]  = *(const short8*)&pA[(wm*32 + i*16 + (lane&15))*64 + kq];
      #pragma unroll
      for (int j=0;j<4;++j)
        bfv[j] = *(const short8*)&pB[(wn*64 + j*16 + (lane&15))*64 + kq];
      #pragma unroll
      for (int i=0;i<2;++i)
        #pragma unroll
        for (int j=0;j<4;++j)
          acc[i][j] = __builtin_amdgcn_mfma_f32_16x16x32_bf16(af[i], bfv[j], acc[i][j], 0,0,0);
    }
    cur ^= 1;
  }
  #undef STAGE

  const int rb = (lane>>4)*4, cb = lane & 15;   // C/D: col=lane&15, row=quad*4+reg
  #pragma unroll
  for (int i=0;i<2;++i)
    #pragma unroll
    for (int r=0;r<4;++r) {
      const int grow = m0 + wm*32 + i*16 + rb + r;
      OutT* Cp = C + (size_t)grow*ldc + n0 + wn*64 + cb;
      #pragma unroll
      for (int j=0;j<4;++j) stv<OutT>(Cp + j*16, acc[i][j][r]);
    }
}

// ---- fused pipeline step: gemm(c) || attn(c-1) || embed(c+1) ----------------
// Block ranges: [0,ngemm) gemm, [ngemm,ngemm+nattn) attn, rest embed.
// gemm blocks first so they seed all CUs; attn/embed blocks fill the tail.
// Buffer audit (double-buffered qkv/hbuf): gemm writes qkv[c&1], reads
// hbuf[c&1]; attn reads qkv[(c-1)&1]; embed writes hbuf[(c+1)&1] -> no
// within-launch hazards; cross-launch deps are stream-ordered.
__global__ __launch_bounds__(512) void fused_step(
    int ngemm, int nattn,
    const bf16* __restrict__ A, const bf16* __restrict__ Bt,
    bf16* __restrict__ Cq, int MT, int NT,
    const bf16* __restrict__ qkv_in, int b0,
    int tok0e, bf16* __restrict__ hout,
    const int* __restrict__ eidx, const void* conf, const void* subw,
    const void* b1, const void* lng, const void* lnb,
    bf16* __restrict__ obar, const float* prep)
{
  __shared__ __align__(16) bf16 sA[2*128*64];   // 32 KB
  __shared__ __align__(16) bf16 sB[2*128*64];   // 32 KB
  const int bid = blockIdx.x;
  if (bid < ngemm){
    gemm_body<bf16>(bid, sA, sB, A, Bt, Cq, HID, HID, HID, 2304, MT, NT);
    return;
  }
  const int isbf = ((const int*)prep)[0];
  if (bid < ngemm + nattn){
    if (isbf) attn_body<bf16 >(bid-ngemm, qkv_in, eidx, subw, obar, b0, prep);
    else      attn_body<float>(bid-ngemm, qkv_in, eidx, subw, obar, b0, prep);
  } else {
    const int eb = bid - ngemm - nattn;
    if (isbf) embed_body<bf16 >(eb, eidx, conf, b1, lng, lnb, prep, hout, tok0e);
    else      embed_body<float>(eb, eidx, conf, b1, lng, lnb, prep, hout, tok0e);
  }
}

__global__ __launch_bounds__(512) void gemm_final(
    const bf16* __restrict__ A, const bf16* __restrict__ Bt, void* C,
    int K, int lda, int ldb, int ldc, int MT, int NT, const float* prep)
{
  __shared__ __align__(16) bf16 sA[2*128*64];
  __shared__ __align__(16) bf16 sB[2*128*64];
  if (((const int*)prep)[0]) gemm_body<bf16 >(blockIdx.x, sA, sB, A, Bt, (bf16*)C,  K, lda, ldb, ldc, MT, NT);
  else                       gemm_body<float>(blockIdx.x, sA, sB, A, Bt, (float*)C, K, lda, ldb, ldc, MT, NT);
}

// ---------------- launch ----------------------------------------------------
extern "C" void kernel_launch(void* const* d_in, const int* in_sizes, int n_in,
                              void* d_out, int out_size, void* d_ws, size_t ws_size,
                              hipStream_t stream)
{
  const int*  eidx = (const int*) d_in[0];
  const void* conf = d_in[1];
  const void* etab = d_in[2];
  const void* W1   = d_in[3];
  const void* b1   = d_in[4];
  const void* lng  = d_in[5];
  const void* lnb  = d_in[6];
  const void* Wq   = d_in[7];
  const void* Wk   = d_in[8];
  const void* Wv   = d_in[9];
  const void* Wo   = d_in[10];
  const void* lq1  = d_in[11];
  const void* lk1  = d_in[12];
  const void* lq2  = d_in[13];
  const void* lk2  = d_in[14];
  const void* subw = d_in[15];

  // ws layout: [prep 36KB][obar][WqkvT][WoT][hbuf x2][qkv x2]
  const size_t PREP_B = 36864ull;
  const size_t OBAR_B = 25165824ull, WQKVT_B = 3538944ull, WOT_B = 1179648ull;
  const size_t FIXED  = PREP_B + OBAR_B + WQKVT_B + WOT_B;

  char*  ws   = (char*)d_ws;
  float* prep = (float*)ws;
  bf16*  obar = (bf16*)(ws + PREP_B);
  bf16* WqkvT = (bf16*)(ws + PREP_B + OBAR_B);
  bf16* WoT   = (bf16*)(ws + PREP_B + OBAR_B + WQKVT_B);

  // per-chunk bytes: 2 x hbuf (CB*4608) + 2 x qkv (CB*13824) = CB*36864
  int CB = 8192;
  while (CB > 1024 && FIXED + (size_t)CB*36864ull > ws_size) CB >>= 1;

  bf16* hb[2] = { (bf16*)(ws + FIXED),
                  (bf16*)(ws + FIXED + (size_t)CB*4608ull) };
  bf16* qk[2] = { (bf16*)(ws + FIXED + (size_t)CB*9216ull),
                  (bf16*)(ws + FIXED + (size_t)CB*9216ull + (size_t)CB*13824ull) };

  const int nchunks = NB / CB;
  const int ctok = 3*CB;
  const int MT = ctok/128, NT = 18;
  const int ngemm = MT*NT;          // MT multiple of 8 -> XCD swizzle active
  const int nattn = CB/8;           // 8 rows/block @512thr
  const int nembed = ctok/32;       // 32 tokens/block @512thr

  setup_kernel<<<2314, 256, 0, stream>>>(etab, W1, b1, lq1, lk1, lq2, lk2,
                                         Wq, Wk, Wv, Wo, WqkvT, WoT, prep);

  // embed chunk 0 -> hb[0]
  fused_step<<<nembed, 512, 0, stream>>>(0, 0, hb[0], WqkvT, qk[0], MT, NT,
                                         qk[0], 0, 0, hb[0],
                                         eidx, conf, subw, b1, lng, lnb, obar, prep);
  for (int c = 0; c < nchunks; ++c) {
    const int na = (c >= 1) ? nattn : 0;
    const int ne = (c+1 < nchunks) ? nembed : 0;
    fused_step<<<ngemm+na+ne, 512, 0, stream>>>(
        ngemm, na,
        hb[c&1], WqkvT, qk[c&1], MT, NT,
        qk[(c&1)^1], (c-1)*CB,
        (c+1)*ctok, hb[(c&1)^1],
        eidx, conf, subw, b1, lng, lnb, obar, prep);
  }
  // last chunk's attention
  fused_step<<<nattn, 512, 0, stream>>>(0, nattn, hb[0], WqkvT, qk[0], MT, NT,
                                        qk[(nchunks-1)&1], (nchunks-1)*CB,
                                        0, hb[0],
                                        eidx, conf, subw, b1, lng, lnb, obar, prep);

  gemm_final<<<128*6, 512, 0, stream>>>(obar, WoT, (void*)d_out, HID, HID, HID, HID, 128, 6, prep);
}

// Round 10
// 410.042 us; speedup vs baseline: 1.0971x; 1.0971x over previous
//
#include <hip/hip_runtime.h>
#include <hip/hip_bf16.h>
#include <math.h>
#include <stdint.h>

typedef __hip_bfloat16 bf16;
typedef __attribute__((ext_vector_type(8))) short short8;   // 8 x bf16 (4 VGPRs)
typedef __attribute__((ext_vector_type(4))) float f32x4;
typedef __attribute__((ext_vector_type(2))) unsigned int u32x2;

#define NB 16384
#define HID 768
#define EPS_LN 1e-5f
#define LAM_INIT 0.2f       // 0.8 - 0.6*exp(-0.3*0)

__device__ __forceinline__ float bf2f(bf16 x){ return __bfloat162float(x); }
__device__ __forceinline__ bf16  f2bf(float x){ return __float2bfloat16(x); }
__device__ __forceinline__ float bfbits(uint32_t lo16){ return __uint_as_float(lo16 << 16); }
__device__ __forceinline__ uint32_t f2bfbits(float x){
  union { float f; uint32_t u; } v; v.f = x;
  uint32_t u = v.u;
  uint32_t r = (u + 0x7fff + ((u >> 16) & 1)) >> 16;   // RNE
  return r;
}

template<typename T> __device__ __forceinline__ float ldv(const void* p, int i);
template<> __device__ __forceinline__ float ldv<float>(const void* p, int i){ return ((const float*)p)[i]; }
template<> __device__ __forceinline__ float ldv<bf16 >(const void* p, int i){ return bf2f(((const bf16*)p)[i]); }

template<typename T> __device__ __forceinline__ void stv(T* p, float v);
template<> __device__ __forceinline__ void stv<float>(float* p, float v){ *p = v; }
template<> __device__ __forceinline__ void stv<bf16 >(bf16*  p, float v){ *p = f2bf(v); }

__device__ __forceinline__ void async_copy16(void* lds, const void* g){
  __builtin_amdgcn_global_load_lds(
      (const __attribute__((address_space(1))) unsigned int*)g,
      (__attribute__((address_space(3))) unsigned int*)lds, 16, 0, 0);
}

__device__ __forceinline__ float wred64(float v){
  #pragma unroll
  for (int m = 1; m <= 32; m <<= 1) v += __shfl_xor(v, m, 64);
  return v;
}

// dtype detect: bf16 inputs have etab row 8 (zeros) at byte offset 512..575.
// Uniform across threads -> no reduction needed.  16 scalar L2-hit loads.
__device__ __forceinline__ int detect_bf(const void* etab){
  const uint32_t* p = (const uint32_t*)((const char*)etab + 512);
  uint32_t v = 0;
  #pragma unroll
  for (int i = 0; i < 16; ++i) v |= p[i];
  return v == 0u ? 1 : 0;
}

// prep float layout:
//   [0]=flag(int), [1]=lam
//   [16+s*32+p]=cos, [128+s*32+p]=sin            (legacy layout, p<24)
//   [256 + (s*24+p)*2 .. +1] = packed {cos,sin}  (p<24)
//   [512+id]=mean(E1[id]), [528+id]=E[E1[id]^2], [544+id]=E[E1[id]*b1]
//   [560]=mean(b1), [561]=E[b1^2]
//   [1024 .. 1024+9*768) = E1 = etab @ W1  (9 x 768, f32)

// ---- setup part 1: lambda + RoPE tables (one block, wave 0) -----------------
__device__ __forceinline__ void misc_body(int isbf, const void* lq1, const void* lk1,
                                          const void* lq2, const void* lk2, float* prep){
  const int lane = threadIdx.x;
  if (lane >= 64) return;
  if (lane == 0) ((int*)prep)[0] = isbf;

  float p1 = 0.f, p2 = 0.f;
  if (lane < 48){
    if (isbf){ p1 = ldv<bf16>(lq1,lane)*ldv<bf16>(lk1,lane); p2 = ldv<bf16>(lq2,lane)*ldv<bf16>(lk2,lane); }
    else     { p1 = ldv<float>(lq1,lane)*ldv<float>(lk1,lane); p2 = ldv<float>(lq2,lane)*ldv<float>(lk2,lane); }
  }
  p1 = wred64(p1); p2 = wred64(p2);
  if (lane == 0) prep[1] = expf(p1) - expf(p2) + LAM_INIT;

  if (lane < 24){
    float invf = powf(10000.f, -(float)(2*lane)/48.f);
    #pragma unroll
    for (int s=0;s<3;++s){
      float ang = (float)s*invf;
      float c = cosf(ang), sv = sinf(ang);
      prep[16  + s*32 + lane] = c;
      prep[128 + s*32 + lane] = sv;
      prep[256 + (s*24 + lane)*2    ] = c;
      prep[256 + (s*24 + lane)*2 + 1] = sv;
    }
  }
}

// ---- setup part 2: E1 = etab @ W1 (one block per id) + closed-form LN stats -
template<typename T>
__device__ __forceinline__ void prep_e1_body(int id, const void* etab, const void* W1,
                                             const void* b1, float* prep,
                                             float (*red)[4]){
  const int tid = threadIdx.x;
  const int wave = tid >> 6, lane = tid & 63;

  float et[32];
  #pragma unroll
  for (int e=0;e<32;++e) et[e] = ldv<T>(etab, id*32+e);

  float su=0.f, suu=0.f, sub=0.f;
  #pragma unroll
  for (int q=0;q<3;++q){
    const int cc = tid + q*256;
    float s = 0.f;
    #pragma unroll
    for (int e=0;e<32;++e) s += et[e]*ldv<T>(W1, e*HID+cc);
    prep[1024 + id*HID + cc] = s;
    float bv = ldv<T>(b1, cc);
    su += s; suu += s*s; sub += s*bv;
  }
  su = wred64(su); suu = wred64(suu); sub = wred64(sub);
  if (lane==0){ red[0][wave]=su; red[1][wave]=suu; red[2][wave]=sub; }
  __syncthreads();
  if (tid==0){
    float a=0.f,b=0.f,c=0.f;
    #pragma unroll
    for (int w=0;w<4;++w){ a+=red[0][w]; b+=red[1][w]; c+=red[2][w]; }
    prep[512+id]=a*(1.f/768.f); prep[528+id]=b*(1.f/768.f); prep[544+id]=c*(1.f/768.f);
  }
  if (id==0){
    float sb=0.f, sbb=0.f;
    #pragma unroll
    for (int q=0;q<3;++q){ float bv=ldv<T>(b1, tid+q*256); sb+=bv; sbb+=bv*bv; }
    sb=wred64(sb); sbb=wred64(sbb);
    __syncthreads();                       // red[] free again
    if (lane==0){ red[0][wave]=sb; red[1][wave]=sbb; }
    __syncthreads();
    if (tid==0){
      float a=0.f,b=0.f;
      #pragma unroll
      for (int w=0;w<4;++w){ a+=red[0][w]; b+=red[1][w]; }
      prep[560]=a*(1.f/768.f); prep[561]=b*(1.f/768.f);
    }
  }
}

// ---- setup part 3: weight transpose (K,N) -> bf16 (N,K) ---------------------
template<typename T>
__device__ __forceinline__ void transpose_body(bf16 (*tile)[33], const void* src,
                                               bf16* dst, int n0, int k0){
  const int tid = threadIdx.x;
  const int tx = tid & 31, ty = tid >> 5;
  #pragma unroll
  for (int r=0;r<4;++r)
    tile[ty + 8*r][tx] = f2bf(ldv<T>(src, (k0 + ty + 8*r)*HID + n0 + tx));
  __syncthreads();
  #pragma unroll
  for (int r=0;r<4;++r)
    dst[(size_t)(n0 + ty + 8*r)*HID + k0 + tx] = tile[tx][ty + 8*r];
}

// ---- one setup launch: blocks [0,2304) transpose, 2304 misc, [2305,2314) E1 -
__global__ __launch_bounds__(256) void setup_kernel(
    const void* etab, const void* W1, const void* b1,
    const void* lq1, const void* lk1, const void* lq2, const void* lk2,
    const void* Wq, const void* Wk, const void* Wv, const void* Wo,
    bf16* __restrict__ WqkvT, bf16* __restrict__ WoT, float* prep)
{
  __shared__ bf16 tile[32][33];
  __shared__ float red[3][4];
  const int bid = blockIdx.x;
  const int isbf = detect_bf(etab);
  if (bid < 2304){
    const int z = bid / 576, rem = bid % 576;
    const int bx = rem % 24, by = rem / 24;
    const void* src = (z==0)? Wq : (z==1)? Wk : (z==2)? Wv : Wo;
    bf16* dst = (z<3)? (WqkvT + (size_t)z*HID*HID) : WoT;
    if (isbf) transpose_body<bf16 >(tile, src, dst, bx*32, by*32);
    else      transpose_body<float>(tile, src, dst, bx*32, by*32);
  } else if (bid == 2304){
    misc_body(isbf, lq1, lk1, lq2, lk2, prep);
  } else {
    if (isbf) prep_e1_body<bf16 >(bid-2305, etab, W1, b1, prep, red);
    else      prep_e1_body<float>(bid-2305, etab, W1, b1, prep, red);
  }
}

// -------- embed via E1 table: h = gelu(LN(conf*E1[id] + b1)) -----------------
template<typename T>
__device__ __forceinline__ void embed_body(
    int bid, const int* eidx, const void* conf, const void* b1, const void* lng,
    const void* lnb, const float* prep, bf16* hout, int tok0)
{
  const int wave = threadIdx.x >> 6, lane = threadIdx.x & 63;
  const int t0 = bid*16 + wave*4;
  const int c  = lane*12;
  float bb[12], gg[12], be[12];
  #pragma unroll
  for (int d=0;d<12;++d){ bb[d]=ldv<T>(b1,c+d); gg[d]=ldv<T>(lng,c+d); be[d]=ldv<T>(lnb,c+d); }
  const float m_b = prep[560], s_bb = prep[561];
  const float* E1 = prep + 1024;

  #pragma unroll
  for (int tt = 0; tt < 4; ++tt){
    const int tl = t0 + tt, tg = tok0 + tl;
    int id = eidx[tg]; if (id < 0) id = 8;
    const float cf = ldv<T>(conf, tg);
    const float4* ep = (const float4*)(E1 + id*HID + c);
    float4 u0 = ep[0], u1 = ep[1], u2 = ep[2];
    float u[12] = {u0.x,u0.y,u0.z,u0.w, u1.x,u1.y,u1.z,u1.w, u2.x,u2.y,u2.z,u2.w};
    const float mu  = cf*prep[512+id] + m_b;
    const float ex2 = cf*cf*prep[528+id] + 2.f*cf*prep[544+id] + s_bb;
    const float var = ex2 - mu*mu;
    const float rs  = rsqrtf(fmaxf(var, 0.f) + EPS_LN);
    uint32_t w[6];
    #pragma unroll
    for (int d=0;d<6;++d){
      float x0 = cf*u[2*d]   + bb[2*d];
      float x1 = cf*u[2*d+1] + bb[2*d+1];
      float y0 = (x0-mu)*rs*gg[2*d]   + be[2*d];
      float y1 = (x1-mu)*rs*gg[2*d+1] + be[2*d+1];
      float g0 = 0.5f*y0*(1.f + erff(y0*0.70710678118f));
      float g1 = 0.5f*y1*(1.f + erff(y1*0.70710678118f));
      w[d] = f2bfbits(g0) | (f2bfbits(g1) << 16);
    }
    char* op = (char*)hout + (size_t)(tl*HID + c)*2;
    ((u32x2*)op)[0] = (u32x2){w[0],w[1]};
    ((u32x2*)op)[1] = (u32x2){w[2],w[3]};
    ((u32x2*)op)[2] = (u32x2){w[4],w[5]};
  }
}

// ---------------- attention: one wave per batch row (all 8 heads) ------------
template<typename T>
__device__ __forceinline__ void attn_body(
    int bid, const bf16* __restrict__ qkv, const int* __restrict__ eidx,
    const void* subw, bf16* __restrict__ obar, int b0, const float* prep)
{
  const int bl = bid*4 + (threadIdx.x>>6);          // chunk-local batch row
  const int bg = b0 + bl;                           // global batch row
  const int lane = threadIdx.x & 63;
  const int h  = lane >> 3;
  const int u  = lane & 7;
  const int g  = u >> 2;
  const int qd = u & 3;

  float npad[3];
  #pragma unroll
  for (int s=0;s<3;++s){ int id = eidx[bg*3+s]; npad[s] = (id < 0 || id == 8) ? 0.f : 1.f; }
  float denom = npad[0]+npad[1]+npad[2]; if (denom < 1.f) denom = 1.f;
  const float lam = prep[1];
  const float2* pk = (const float2*)(prep + 256);

  const char* base = (const char*)(qkv + (size_t)bl*3*2304);
  const int qoff = (2*h+g)*48 + qd*12;              // element offset in token row

  u32x2 qw[3][3], kw[3][3];
  #pragma unroll
  for (int s=0;s<3;++s){
    const char* qp = base + (size_t)(s*2304 + qoff)*2;
    const char* kp = qp + 768*2;
    #pragma unroll
    for (int t=0;t<3;++t){
      qw[s][t] = *(const u32x2*)(qp + t*8);
      kw[s][t] = *(const u32x2*)(kp + t*8);
    }
  }

  float sc[3][3];
  #pragma unroll
  for (int a=0;a<3;++a){ sc[a][0]=0.f; sc[a][1]=0.f; sc[a][2]=0.f; }
  #pragma unroll
  for (int j=0;j<6;++j){
    float qr1[3], qr2[3], kr1[3], kr2[3];
    #pragma unroll
    for (int s=0;s<3;++s){
      float2 cs = pk[s*24 + qd*6 + j];
      uint32_t qu = qw[s][j>>1][j&1], ku = kw[s][j>>1][j&1];
      float q1 = bfbits(qu & 0xffffu), q2 = bfbits(qu >> 16);
      float k1 = bfbits(ku & 0xffffu), k2 = bfbits(ku >> 16);
      qr1[s] = q1*cs.x - q2*cs.y;  qr2[s] = q1*cs.y + q2*cs.x;
      kr1[s] = k1*cs.x - k2*cs.y;  kr2[s] = k1*cs.y + k2*cs.x;
    }
    #pragma unroll
    for (int a=0;a<3;++a)
      #pragma unroll
      for (int b=0;b<3;++b) sc[a][b] += qr1[a]*kr1[b] + qr2[a]*kr2[b];
  }
  #pragma unroll
  for (int a=0;a<3;++a)
    #pragma unroll
    for (int b=0;b<3;++b){
      float v = sc[a][b];
      v += __shfl_xor(v, 1, 64);
      v += __shfl_xor(v, 2, 64);
      sc[a][b] = v;
    }

  const float scale = 0.14433756729740643f;  // 48^-0.5
  float att[3][3];
  #pragma unroll
  for (int a=0;a<3;++a){
    float s0 = sc[a][0]*scale + (npad[0] > 0.f ? 0.f : -1e30f);
    float s1 = sc[a][1]*scale + (npad[1] > 0.f ? 0.f : -1e30f);
    float s2 = sc[a][2]*scale + (npad[2] > 0.f ? 0.f : -1e30f);
    float mx = fmaxf(s0, fmaxf(s1, s2));
    float e0 = expf(s0-mx), e1 = expf(s1-mx), e2 = expf(s2-mx);
    float inv = 1.f/(e0+e1+e2);
    att[a][0]=e0*inv; att[a][1]=e1*inv; att[a][2]=e2*inv;
  }
  float diff[3][3];
  #pragma unroll
  for (int a=0;a<3;++a)
    #pragma unroll
    for (int b=0;b<3;++b){
      float other = __shfl_xor(att[a][b], 4, 64);
      diff[a][b] = (g==0) ? (att[a][b] - lam*other) : (other - lam*att[a][b]);
    }

  const int vd = u*12;
  float vv[3][12];
  #pragma unroll
  for (int s=0;s<3;++s){
    const char* vp = base + (size_t)(s*2304 + 1536 + h*96 + vd)*2;
    #pragma unroll
    for (int t=0;t<3;++t){
      u32x2 w = *(const u32x2*)(vp + t*8);
      vv[s][t*4+0] = bfbits(w[0] & 0xffffu);
      vv[s][t*4+1] = bfbits(w[0] >> 16);
      vv[s][t*4+2] = bfbits(w[1] & 0xffffu);
      vv[s][t*4+3] = bfbits(w[1] >> 16);
    }
  }
  float sw[12];
  #pragma unroll
  for (int d=0;d<12;++d) sw[d] = ldv<T>(subw, vd + d);

  float acc[12];
  #pragma unroll
  for (int d=0;d<12;++d) acc[d] = 0.f;
  #pragma unroll
  for (int a=0;a<3;++a){
    float o[12]; float ss = 0.f;
    #pragma unroll
    for (int d=0;d<12;++d){
      o[d] = diff[a][0]*vv[0][d] + diff[a][1]*vv[1][d] + diff[a][2]*vv[2][d];
      ss += o[d]*o[d];
    }
    ss += __shfl_xor(ss, 1, 64);
    ss += __shfl_xor(ss, 2, 64);
    ss += __shfl_xor(ss, 4, 64);                  // sum over 96 dims of head h
    float rms = sqrtf(ss*(1.f/96.f) + 1e-5f);
    float kk  = npad[a]*0.8f/rms;                 // includes *(1-LAMBDA_INIT)
    #pragma unroll
    for (int d=0;d<12;++d) acc[d] += o[d]*kk*sw[d];
  }
  const float idn = 1.f/denom;
  char* op = (char*)obar + (size_t)(bg*HID + h*96 + vd)*2;
  #pragma unroll
  for (int t=0;t<3;++t){
    u32x2 w;
    w[0] = f2bfbits(acc[t*4+0]*idn) | (f2bfbits(acc[t*4+1]*idn) << 16);
    w[1] = f2bfbits(acc[t*4+2]*idn) | (f2bfbits(acc[t*4+3]*idn) << 16);
    *(u32x2*)(op + t*8) = w;
  }
}

// ---- merged attn(c) + embed(c+1): independent work, overlapped in one launch
__global__ __launch_bounds__(256) void attn_embed(
    const bf16* __restrict__ qkv, const int* __restrict__ eidx, const void* subw,
    bf16* __restrict__ obar, int b0, const float* prep,
    const void* conf, const void* b1, const void* lng, const void* lnb,
    bf16* __restrict__ hout, int tok0e, int nattn)
{
  const int isbf = ((const int*)prep)[0];
  if ((int)blockIdx.x < nattn){
    if (isbf) attn_body<bf16 >(blockIdx.x, qkv, eidx, subw, obar, b0, prep);
    else      attn_body<float>(blockIdx.x, qkv, eidx, subw, obar, b0, prep);
  } else {
    const int eb = blockIdx.x - nattn;
    if (isbf) embed_body<bf16 >(eb, eidx, conf, b1, lng, lnb, prep, hout, tok0e);
    else      embed_body<float>(eb, eidx, conf, b1, lng, lnb, prep, hout, tok0e);
  }
}

// ------- 128x128 MFMA GEMM, 8 waves (512 thr): dbuf + XCD + LDS XOR swizzle --
// Round-8 verified: wave grid 4Mx2N, 32x64 output/wave, 64KB LDS, 52 VGPR,
// 0 bank conflicts, ~111us at 24576x2304x768 (MfmaUtil 34, Occ 40).
// Closed dead-ends at this shape: 8-phase 256^2 (r1, -8%), BK=32/5-block
// (r5, -54%), heterogeneous block fusion (r9, -5%: light blocks reserve the
// same 64KB LDS slots and displace gemm blocks).
template<typename OutT>
__device__ __forceinline__ void gemm_body(
    bf16* sA, bf16* sB,     // each 2*128*64 elements (two buffers)
    const bf16* __restrict__ A, const bf16* __restrict__ Bt, OutT* __restrict__ C,
    int K, int lda, int ldb, int ldc, int MT, int NT)
{
  int bid = blockIdx.x;
  int mt, nt;
  if ((MT & 7) == 0) {
    int x = bid & 7, j = bid >> 3;
    nt = j % NT;
    mt = x * (MT >> 3) + j / NT;
  } else { nt = bid % NT; mt = bid / NT; }

  const int tid = threadIdx.x;
  const int wave = tid >> 6, lane = tid & 63;       // wave 0..7
  const int m0 = mt * 128, n0 = nt * 128;
  const int wm = wave >> 1, wn = wave & 1;          // 4M x 2N wave grid

  f32x4 acc[2][4];
  #pragma unroll
  for (int i=0;i<2;++i)
    #pragma unroll
    for (int j=0;j<4;++j) acc[i][j] = (f32x4){0.f,0.f,0.f,0.f};

  const char* Ag = (const char*)(A  + (size_t)m0 * lda);
  const char* Bg = (const char*)(Bt + (size_t)n0 * ldb);
  const int r8  = lane >> 3;                       // row within 8-row group (0..7)
  const int cBx = ((lane & 7) ^ r8) * 16;          // XOR-permuted k-group source

  #define STAGE(buf, kt) do {                                                   \
    _Pragma("unroll")                                                           \
    for (int ii = 0; ii < 2; ++ii) {                                            \
      const int i_ = wave*2 + ii;                                               \
      const int row_ = i_*8 + r8;                                               \
      async_copy16((char*)sA + (buf)*16384 + i_*1024 + lane*16,                 \
                   Ag + ((size_t)row_*lda + (kt))*2 + cBx);                     \
      async_copy16((char*)sB + (buf)*16384 + i_*1024 + lane*16,                 \
                   Bg + ((size_t)row_*ldb + (kt))*2 + cBx);                     \
    }                                                                           \
  } while(0)

  STAGE(0, 0);
  int cur = 0;
  const int rxor = (lane & 7) << 3;                // reader phys-k XOR (row&7)*8
  for (int kt = 0; kt < K; kt += 64) {
    __syncthreads();
    if (kt + 64 < K) STAGE(cur^1, kt + 64);   // prefetch overlaps compute below
    const bf16* pA = sA + cur*8192;
    const bf16* pB = sB + cur*8192;
    #pragma unroll
    for (int ks = 0; ks < 64; ks += 32) {
      const int kq = (ks + (lane >> 4)*8) ^ rxor;
      short8 af[2], bfv[4];
      #pragma unroll
      for (int i=0;i<2;++i)
        af[i]  = *(const short8*)&pA[(wm*32 + i*16 + (lane&15))*64 + kq];
      #pragma unroll
      for (int j=0;j<4;++j)
        bfv[j] = *(const short8*)&pB[(wn*64 + j*16 + (lane&15))*64 + kq];
      #pragma unroll
      for (int i=0;i<2;++i)
        #pragma unroll
        for (int j=0;j<4;++j)
          acc[i][j] = __builtin_amdgcn_mfma_f32_16x16x32_bf16(af[i], bfv[j], acc[i][j], 0,0,0);
    }
    cur ^= 1;
  }
  #undef STAGE

  const int rb = (lane>>4)*4, cb = lane & 15;   // C/D: col=lane&15, row=quad*4+reg
  #pragma unroll
  for (int i=0;i<2;++i)
    #pragma unroll
    for (int r=0;r<4;++r) {
      const int grow = m0 + wm*32 + i*16 + rb + r;
      OutT* Cp = C + (size_t)grow*ldc + n0 + wn*64 + cb;
      #pragma unroll
      for (int j=0;j<4;++j) stv<OutT>(Cp + j*16, acc[i][j][r]);
    }
}

__global__ __launch_bounds__(512) void gemm_int(
    const bf16* __restrict__ A, const bf16* __restrict__ Bt, bf16* __restrict__ C,
    int K, int lda, int ldb, int ldc, int MT, int NT)
{
  __shared__ __align__(16) bf16 sA[2*128*64];   // 32 KB
  __shared__ __align__(16) bf16 sB[2*128*64];   // 32 KB
  gemm_body<bf16>(sA, sB, A, Bt, C, K, lda, ldb, ldc, MT, NT);
}

__global__ __launch_bounds__(512) void gemm_final(
    const bf16* __restrict__ A, const bf16* __restrict__ Bt, void* C,
    int K, int lda, int ldb, int ldc, int MT, int NT, const float* prep)
{
  __shared__ __align__(16) bf16 sA[2*128*64];
  __shared__ __align__(16) bf16 sB[2*128*64];
  if (((const int*)prep)[0]) gemm_body<bf16 >(sA, sB, A, Bt, (bf16*)C,  K, lda, ldb, ldc, MT, NT);
  else                       gemm_body<float>(sA, sB, A, Bt, (float*)C, K, lda, ldb, ldc, MT, NT);
}

// ---------------- launch ----------------------------------------------------
extern "C" void kernel_launch(void* const* d_in, const int* in_sizes, int n_in,
                              void* d_out, int out_size, void* d_ws, size_t ws_size,
                              hipStream_t stream)
{
  const int*  eidx = (const int*) d_in[0];
  const void* conf = d_in[1];
  const void* etab = d_in[2];
  const void* W1   = d_in[3];
  const void* b1   = d_in[4];
  const void* lng  = d_in[5];
  const void* lnb  = d_in[6];
  const void* Wq   = d_in[7];
  const void* Wk   = d_in[8];
  const void* Wv   = d_in[9];
  const void* Wo   = d_in[10];
  const void* lq1  = d_in[11];
  const void* lk1  = d_in[12];
  const void* lq2  = d_in[13];
  const void* lk2  = d_in[14];
  const void* subw = d_in[15];

  // ws layout: [prep 36KB (incl. E1 table)][obar][WqkvT][WoT][hbuf][qkv]
  const size_t PREP_B = 36864ull;
  const size_t OBAR_B = 25165824ull, WQKVT_B = 3538944ull, WOT_B = 1179648ull;
  const size_t FIXED  = PREP_B + OBAR_B + WQKVT_B + WOT_B;

  char*  ws   = (char*)d_ws;
  float* prep = (float*)ws;
  bf16*  obar = (bf16*)(ws + PREP_B);
  bf16* WqkvT = (bf16*)(ws + PREP_B + OBAR_B);
  bf16* WoT   = (bf16*)(ws + PREP_B + OBAR_B + WQKVT_B);

  // largest power-of-two chunk of batch rows that fits (min 128)
  int CB = NB;
  while (CB > 128 && FIXED + (size_t)CB*18432ull > ws_size) CB >>= 1;

  bf16* hbuf = (bf16*)(ws + FIXED);
  bf16* qkv  = (bf16*)(ws + FIXED + (size_t)CB*4608ull);

  setup_kernel<<<2314, 256, 0, stream>>>(etab, W1, b1, lq1, lk1, lq2, lk2,
                                         Wq, Wk, Wv, Wo, WqkvT, WoT, prep);

  const int nchunks = NB / CB;
  const int ctok = 3*CB;                      // tokens per chunk (mult of 384)
  // embed chunk 0 (attn part empty)
  attn_embed<<<ctok/16, 256, 0, stream>>>(qkv, eidx, subw, obar, 0, prep,
                                          conf, b1, lng, lnb, hbuf, 0, 0);
  for (int c = 0; c < nchunks; ++c) {
    const int MT = ctok/128, NT = 18;
    gemm_int<<<MT*NT, 512, 0, stream>>>(hbuf, WqkvT, qkv, HID, HID, HID, 2304, MT, NT);
    const int na = CB/4;
    const int ne = (c+1 < nchunks) ? ctok/16 : 0;
    attn_embed<<<na+ne, 256, 0, stream>>>(qkv, eidx, subw, obar, c*CB, prep,
                                          conf, b1, lng, lnb, hbuf, (c+1)*ctok, na);
  }

  gemm_final<<<128*6, 512, 0, stream>>>(obar, WoT, (void*)d_out, HID, HID, HID, HID, 128, 6, prep);
}